// Round 1
// baseline (56.015 us; speedup 1.0000x reference)
//
#include <hip/hip_runtime.h>
#include <math.h>

#define N 512
#define D 256
#define ITILE 2
#define TPB 512

__constant__ float kRad2Deg = 57.29577951308232f; // 180/pi

// ---------------------------------------------------------------------------
// Kernel 1: per-row pose prep. labels[i] = 6d rot || 3d translation.
// Writes rot (512x9, det-normalized) and t (512x3) to workspace.
// ---------------------------------------------------------------------------
__global__ void prep_kernel(const float* __restrict__ labels,
                            float* __restrict__ rot,
                            float* __restrict__ tvec) {
    int i = blockIdx.x * blockDim.x + threadIdx.x;
    if (i >= N) return;
    const float* p = labels + i * 9;
    float a1x = p[0], a1y = p[1], a1z = p[2];
    float a2x = p[3], a2y = p[4], a2z = p[5];
    float n1 = sqrtf(a1x * a1x + a1y * a1y + a1z * a1z);
    float b1x = a1x / n1, b1y = a1y / n1, b1z = a1z / n1;
    float dp = b1x * a2x + b1y * a2y + b1z * a2z;
    float cx = a2x - dp * b1x, cy = a2y - dp * b1y, cz = a2z - dp * b1z;
    float n2 = sqrtf(cx * cx + cy * cy + cz * cz);
    float b2x = cx / n2, b2y = cy / n2, b2z = cz / n2;
    float b3x = b1y * b2z - b1z * b2y;
    float b3y = b1z * b2x - b1x * b2z;
    float b3z = b1x * b2y - b1y * b2x;
    // det([b1;b2;b3]); ~1 for orthonormal right-handed, but match reference's
    // det^(1/3) normalization exactly.
    float det = b1x * (b2y * b3z - b2z * b3y)
              - b1y * (b2x * b3z - b2z * b3x)
              + b1z * (b2x * b3y - b2y * b3x);
    float inv = 1.0f / cbrtf(det);
    float* r = rot + i * 9;
    r[0] = b1x * inv; r[1] = b1y * inv; r[2] = b1z * inv;
    r[3] = b2x * inv; r[4] = b2y * inv; r[5] = b2z * inv;
    r[6] = b3x * inv; r[7] = b3y * inv; r[8] = b3z * inv;
    tvec[i * 3 + 0] = p[6];
    tvec[i * 3 + 1] = p[7];
    tvec[i * 3 + 2] = p[8];
}

// ---------------------------------------------------------------------------
// Kernel 2: fused. Block handles ITILE=2 full rows i. Computes the row's
// E (exp logits, diag forced 0), TD (theta deg), SD (shift*100) into LDS,
// then the O(n^2)-per-row masked denominator sums entirely from LDS
// (uniform-k broadcast reads -> conflict free). Row-max subtraction is a
// provable no-op (diag logit == 0, off-diag <= 0), so E = exp(logit) directly.
// ---------------------------------------------------------------------------
__global__ __launch_bounds__(TPB) void fused_kernel(
        const float* __restrict__ f,
        const float* __restrict__ rot,
        const float* __restrict__ tvec,
        float* __restrict__ acc) {
    __shared__ __attribute__((aligned(16))) float lds_fi[ITILE * D];
    __shared__ __attribute__((aligned(16))) float E2[ITILE][N];
    __shared__ __attribute__((aligned(16))) float TD2[ITILE][N];
    __shared__ __attribute__((aligned(16))) float SD2[ITILE][N];
    __shared__ float red[TPB / 64];

    const int j  = threadIdx.x;      // column this thread owns
    const int i0 = blockIdx.x * ITILE;

    // stage the block's ITILE feature rows (contiguous: rows i0, i0+1)
    lds_fi[j] = f[i0 * D + j];       // TPB == ITILE*D
    __syncthreads();

    // ---- pairwise distances: d2[r] = || f[i0+r] - f[j] ||^2 ----
    float d2[ITILE];
#pragma unroll
    for (int r = 0; r < ITILE; ++r) d2[r] = 0.0f;

    const float4* __restrict__ fj4 = (const float4*)(f + j * D);
#pragma unroll 8
    for (int kk = 0; kk < D / 4; ++kk) {
        float4 v = fj4[kk];
#pragma unroll
        for (int r = 0; r < ITILE; ++r) {
            const float4 fi = *(const float4*)&lds_fi[r * D + kk * 4];
            float dx = fi.x - v.x, dy = fi.y - v.y;
            float dz = fi.z - v.z, dw = fi.w - v.w;
            d2[r] += dx * dx + dy * dy + dz * dz + dw * dw;
        }
    }

    // ---- pose errors + logits for this column ----
    float rj[9];
#pragma unroll
    for (int c = 0; c < 9; ++c) rj[c] = rot[j * 9 + c];
    const float tjx = tvec[j * 3 + 0];
    const float tjy = tvec[j * 3 + 1];
    const float tjz = tvec[j * 3 + 2];

    float Lv[ITILE];
#pragma unroll
    for (int r = 0; r < ITILE; ++r) {
        const int i = i0 + r;
        float tr = 0.0f;
#pragma unroll
        for (int c = 0; c < 9; ++c) tr += rot[i * 9 + c] * rj[c];  // uniform i -> s_load
        float ct = (tr - 1.0f) * 0.5f;
        ct = fminf(1.0f, fmaxf(-1.0f, ct));
        float theta = acosf(ct) * kRad2Deg;

        float dx = tvec[i * 3 + 0] - tjx;
        float dy = tvec[i * 3 + 1] - tjy;
        float dz = tvec[i * 3 + 2] - tjz;
        float sd2 = dx * dx + dy * dy + dz * dz;
        float shift = (sd2 > 0.0f ? sqrtf(sd2) : 0.0f) * 100.0f;

        float dist = (d2[r] > 0.0f ? sqrtf(d2[r]) : 0.0f);
        float L = -dist * 0.5f;                 // TEMPERATURE = 2.0; rowmax == 0
        float E = (j == i) ? 0.0f : expf(L);    // diag weight 0 == diag removal
        Lv[r] = L;
        E2[r][j]  = E;
        TD2[r][j] = theta;
        SD2[r][j] = shift;
    }
    __syncthreads();

    // ---- masked denominator sums (brute force O(n) per (i,j)) ----
    float vsum = 0.0f;
#pragma unroll
    for (int r = 0; r < ITILE; ++r) {
        const int i = i0 + r;
        if (j == i) continue;                   // j is a threshold only if j != i
        const float tdj = TD2[r][j];
        const float sdj = SD2[r][j];
        float dt = 0.0f, ds = 0.0f;
        for (int k = 0; k < N; k += 4) {
            float4 e4 = *(const float4*)&E2[r][k];
            float4 t4 = *(const float4*)&TD2[r][k];
            float4 s4 = *(const float4*)&SD2[r][k];
            dt += (t4.x >= tdj ? e4.x : 0.0f);
            dt += (t4.y >= tdj ? e4.y : 0.0f);
            dt += (t4.z >= tdj ? e4.z : 0.0f);
            dt += (t4.w >= tdj ? e4.w : 0.0f);
            ds += (s4.x >= sdj ? e4.x : 0.0f);
            ds += (s4.y >= sdj ? e4.y : 0.0f);
            ds += (s4.z >= sdj ? e4.z : 0.0f);
            ds += (s4.w >= sdj ? e4.w : 0.0f);
        }
        // pos_log_prob = (2L - log dt - log ds) / 2 = L - 0.5*(log dt + log ds)
        vsum += Lv[r] - 0.5f * (logf(dt) + logf(ds));
    }

    // ---- block reduction -> single atomic per block ----
#pragma unroll
    for (int off = 32; off > 0; off >>= 1) vsum += __shfl_down(vsum, off, 64);
    const int lane = j & 63, wid = j >> 6;
    if (lane == 0) red[wid] = vsum;
    __syncthreads();
    if (j == 0) {
        float s = 0.0f;
#pragma unroll
        for (int w = 0; w < TPB / 64; ++w) s += red[w];
        atomicAdd(acc, s);
    }
}

// ---------------------------------------------------------------------------
// Kernel 3: finalize scalar.
// ---------------------------------------------------------------------------
__global__ void finalize_kernel(const float* __restrict__ acc,
                                float* __restrict__ out) {
    out[0] = -acc[0] / (float)(N * (N - 1));
}

extern "C" void kernel_launch(void* const* d_in, const int* in_sizes, int n_in,
                              void* d_out, int out_size, void* d_ws, size_t ws_size,
                              hipStream_t stream) {
    const float* f      = (const float*)d_in[0];  // (512, 256) fp32
    const float* labels = (const float*)d_in[1];  // (512, 9)   fp32
    float* out = (float*)d_out;                   // scalar fp32
    float* ws  = (float*)d_ws;

    float* rot  = ws;             // 512*9 floats
    float* tvec = ws + N * 9;     // 512*3 floats
    float* acc  = ws + N * 12;    // 1 float

    hipMemsetAsync(acc, 0, sizeof(float), stream);
    prep_kernel<<<(N + 255) / 256, 256, 0, stream>>>(labels, rot, tvec);
    fused_kernel<<<N / ITILE, TPB, 0, stream>>>(f, rot, tvec, acc);
    finalize_kernel<<<1, 1, 0, stream>>>(acc, out);
}